// Round 2
// baseline (1082.985 us; speedup 1.0000x reference)
//
#include <hip/hip_runtime.h>

// Problem constants (from reference)
constexpr int N_FRAMES   = 2000;
constexpr int BATCH      = 32;
constexpr int TARGET_LEN = 1000;
constexpr int VOCAB      = 256;
constexpr int PF         = 8;      // emit prefetch depth (rows in flight)
#define NEG (-1e30f)

// One block per batch item. Thread j owns DP column j.
// alpha row in LDS, double buffered. Raw s_barrier (NO vmcnt drain) so the
// deep emit-gather prefetch stays in flight across row barriers.
__global__ __launch_bounds__(1024)
void align_dp_kernel(const float* __restrict__ scores,   // [N, B, V]
                     const int*   __restrict__ targets,  // [B, T]
                     const int*   __restrict__ in_len,   // [B]
                     const int*   __restrict__ tg_len,   // [B]
                     float*       __restrict__ ws_final) // [B]
{
    const int b   = blockIdx.x;
    const int tid = threadIdx.x;

    __shared__ float abuf[2][TARGET_LEN];

    const int inlen = in_len[b];
    const int tlen  = tg_len[b];

    const bool active = (tid < TARGET_LEN);
    int tok = 0;
    if (active) tok = targets[b * TARGET_LEN + tid];

    // Column gather pointer: scores[i, b, tok] = scores + i*B*V + b*V + tok
    const float* col = scores + (size_t)b * VOCAB + tok;
    const size_t rstride = (size_t)BATCH * VOCAB;

    // ---- row 0 ----
    float a0 = NEG;
    if (active) {
        float e0 = col[0];
        a0 = (tid == 0) ? e0 : NEG;
        abuf[0][tid] = a0;
        if (inlen == 1 && tid == tlen - 1) ws_final[b] = a0;  // safety (inlen>=1000 in practice)
    }

    // ---- deep register ring prefetch of emit rows 1..PF ----
    float e[PF];
#pragma unroll
    for (int k = 0; k < PF; ++k)
        e[k] = active ? col[(size_t)(1 + k) * rstride] : 0.0f;

    // ---- rows 1..N-1 (last unrolled block computes one harmless dummy row) ----
    int p = 0;
    for (int ib = 1; ib < N_FRAMES; ib += PF) {
#pragma unroll
        for (int k = 0; k < PF; ++k) {
            const int i = ib + k;
            const float ecur = e[k];
            // refill ring slot with row i+PF (stays in flight across barriers)
            if (active && (i + PF) < N_FRAMES)
                e[k] = col[(size_t)(i + PF) * rstride];

            // LDS-only ordering: drain own ds ops, raw barrier (no vmcnt drain),
            // compiler-level fences pin ds_read placement after the barrier.
            asm volatile("s_waitcnt lgkmcnt(0)" ::: "memory");
            __builtin_amdgcn_s_barrier();
            asm volatile("" ::: "memory");

            if (active && i < N_FRAMES) {
                const float ai = abuf[p][tid];
                const float al = (tid > 0) ? abuf[p][tid - 1] : NEG;
                // logaddexp(al, ai)
                const float m = fmaxf(ai, al);
                const float d = fminf(ai, al) - m;        // <= 0
                const float v = ecur + m + __logf(1.0f + __expf(d));
                abuf[p ^ 1][tid] = v;
                if (i == inlen - 1 && tid == tlen - 1) ws_final[b] = v;
            }
            p ^= 1;
        }
    }
}

// Final scalar: out = -sum(ws_final)/BATCH. Unconditional write -> deterministic
// across graph replays regardless of buffer poisoning.
__global__ void reduce_kernel(const float* __restrict__ ws_final, float* __restrict__ out)
{
    if (threadIdx.x == 0 && blockIdx.x == 0) {
        float s = 0.0f;
        for (int b = 0; b < BATCH; ++b) s += ws_final[b];
        out[0] = -s / (float)BATCH;
    }
}

extern "C" void kernel_launch(void* const* d_in, const int* in_sizes, int n_in,
                              void* d_out, int out_size, void* d_ws, size_t ws_size,
                              hipStream_t stream)
{
    const float* scores  = (const float*)d_in[0];
    const int*   targets = (const int*)  d_in[1];
    const int*   in_len  = (const int*)  d_in[2];
    const int*   tg_len  = (const int*)  d_in[3];
    float*       out     = (float*)d_out;
    float*       ws      = (float*)d_ws;   // BATCH floats of scratch

    align_dp_kernel<<<BATCH, 1024, 0, stream>>>(scores, targets, in_len, tg_len, ws);
    reduce_kernel<<<1, 64, 0, stream>>>(ws, out);
}

// Round 3
// 1023.498 us; speedup vs baseline: 1.0581x; 1.0581x over previous
//
#include <hip/hip_runtime.h>

// Problem constants (from reference)
constexpr int N_FRAMES   = 2000;
constexpr int BATCH      = 32;
constexpr int TARGET_LEN = 1000;
constexpr int VOCAB      = 256;
constexpr int COLS_PER_LANE = 16;   // 64 lanes * 16 = 1024 >= 1000 columns
constexpr int RING       = 4;       // emit prefetch depth (rows in registers)
#define NEGF (-1e30f)

// Guaranteed-global (addrspace 1) load type: emits global_load_dword (vmcnt
// only), NEVER flat_load (which would also count in lgkmcnt and get drained
// by the shfl's ds_bpermute waits -- the R1 failure mode).
typedef __attribute__((address_space(1))) const float* gcfp;

// One WAVE per batch item. Lane L owns columns [16L, 16L+15].
// Entire DP state in registers; only cross-lane op is one __shfl_up per row.
// No barriers, no LDS tiles. Log2-domain recurrence:
//   B = alpha * log2(e);  B[i,j] = fma(e, L2E, max(Bl,Bu) + log2(1 + 2^(-|Bl-Bu|)))
__global__ __launch_bounds__(64)
void align_dp_wave(const float* __restrict__ scores,   // [N, B, V]
                   const int*   __restrict__ targets,  // [B, T]
                   const int*   __restrict__ in_len,   // [B]
                   const int*   __restrict__ tg_len,   // [B]
                   float*       __restrict__ ws_final) // [B]
{
    constexpr float L2E = 1.44269504088896340736f;  // log2(e)
    constexpr float LN2 = 0.69314718055994530942f;  // 1/L2E

    const int b    = blockIdx.x;
    const int lane = threadIdx.x;

    const int inlen = in_len[b];
    const int tlen  = tg_len[b];

    const gcfp gsc = (gcfp)scores;
    constexpr unsigned ROWW = (unsigned)(BATCH * VOCAB);  // words per frame row

    // Word indices of my 16 gather columns at the next row to load.
    unsigned widx[COLS_PER_LANE];
#pragma unroll
    for (int c = 0; c < COLS_PER_LANE; ++c) {
        const int col = lane * COLS_PER_LANE + c;
        const int tok = (col < TARGET_LEN) ? targets[b * TARGET_LEN + col] : 0;
        widx[c] = (unsigned)(b * VOCAB + tok);            // row 0
    }

    // ---- row 0: init prev (B domain) ----
    float prev[COLS_PER_LANE];
#pragma unroll
    for (int c = 0; c < COLS_PER_LANE; ++c) {
        const float e0 = gsc[widx[c]];
        const int col  = lane * COLS_PER_LANE + c;
        prev[c] = (col == 0) ? e0 * L2E : NEGF;
        widx[c] += ROWW;
    }
    if (inlen == 1 && (tlen - 1) >> 4 == lane) {          // impossible with this setup, cheap safety
        float v = NEGF;
#pragma unroll
        for (int c = 0; c < COLS_PER_LANE; ++c) if (c == ((tlen - 1) & 15)) v = prev[c];
        ws_final[b] = v * LN2;
    }

    // ---- fill ring with emit rows 1..RING ----
    float ring[RING][COLS_PER_LANE];
#pragma unroll
    for (int k = 0; k < RING; ++k) {
#pragma unroll
        for (int c = 0; c < COLS_PER_LANE; ++c) {
            ring[k][c] = gsc[widx[c]];
            widx[c] += ROWW;
        }
    }

    // ---- rows 1..N-1, unrolled by RING so ring indices are static ----
    for (int ib = 1; ib < N_FRAMES; ib += RING) {
#pragma unroll
        for (int k = 0; k < RING; ++k) {
            const int i = ib + k;
            if (i < N_FRAMES) {
                // left neighbor's last column of previous row (lane boundary)
                float left = __shfl_up(prev[COLS_PER_LANE - 1], 1);
                if (lane == 0) left = NEGF;

                float cur[COLS_PER_LANE];
                // Cells c=1..15 first (register-only), c=0 last so the shfl's
                // ds_bpermute latency hides behind them.
#pragma unroll
                for (int c = 1; c < COLS_PER_LANE; ++c) {
                    const float a = prev[c - 1];
                    const float u = prev[c];
                    const float m = fmaxf(a, u);
                    const float t = m + __builtin_amdgcn_logf(
                                        1.0f + __builtin_amdgcn_exp2f(-fabsf(a - u)));
                    cur[c] = fmaf(ring[k][c], L2E, t);
                }
                {
                    const float a = left;
                    const float u = prev[0];
                    const float m = fmaxf(a, u);
                    const float t = m + __builtin_amdgcn_logf(
                                        1.0f + __builtin_amdgcn_exp2f(-fabsf(a - u)));
                    cur[0] = fmaf(ring[k][0], L2E, t);
                }

                // refill ring slot with row i+RING (stays in flight ~4 rows)
                if (i + RING < N_FRAMES) {
#pragma unroll
                    for (int c = 0; c < COLS_PER_LANE; ++c) {
                        ring[k][c] = gsc[widx[c]];
                        widx[c] += ROWW;
                    }
                }

                if (i == inlen - 1 && ((tlen - 1) >> 4) == lane) {
                    float v = NEGF;
#pragma unroll
                    for (int c = 0; c < COLS_PER_LANE; ++c) if (c == ((tlen - 1) & 15)) v = cur[c];
                    ws_final[b] = v * LN2;
                }

#pragma unroll
                for (int c = 0; c < COLS_PER_LANE; ++c) prev[c] = cur[c];
            }
        }
    }
}

// Final scalar: out = -sum(ws_final)/BATCH. Unconditional write -> deterministic
// across graph replays regardless of buffer poisoning.
__global__ void reduce_kernel(const float* __restrict__ ws_final, float* __restrict__ out)
{
    if (threadIdx.x == 0 && blockIdx.x == 0) {
        float s = 0.0f;
        for (int b = 0; b < BATCH; ++b) s += ws_final[b];
        out[0] = -s / (float)BATCH;
    }
}

extern "C" void kernel_launch(void* const* d_in, const int* in_sizes, int n_in,
                              void* d_out, int out_size, void* d_ws, size_t ws_size,
                              hipStream_t stream)
{
    const float* scores  = (const float*)d_in[0];
    const int*   targets = (const int*)  d_in[1];
    const int*   in_len  = (const int*)  d_in[2];
    const int*   tg_len  = (const int*)  d_in[3];
    float*       out     = (float*)d_out;
    float*       ws      = (float*)d_ws;   // BATCH floats of scratch

    align_dp_wave<<<BATCH, 64, 0, stream>>>(scores, targets, in_len, tg_len, ws);
    reduce_kernel<<<1, 64, 0, stream>>>(ws, out);
}

// Round 4
// 543.742 us; speedup vs baseline: 1.9917x; 1.8823x over previous
//
#include <hip/hip_runtime.h>

// Problem constants (from reference)
constexpr int N_FRAMES   = 2000;
constexpr int BATCH      = 32;
constexpr int TARGET_LEN = 1000;
constexpr int VOCAB      = 256;
constexpr int NTH        = 256;   // 4 waves per block
constexpr int CPT        = 4;     // columns per thread (256*4 = 1024 >= 1000)
#define NEGF (-1e30f)

// addrspace(1) pointer => guaranteed global_load (vmcnt only, never flat).
typedef __attribute__((address_space(1))) const float* gcfp;

// logaddexp in log2 domain: dst = E*log2e + max(A,U) + log2(1 + 2^(-|A-U|))
#define CELL(dst, A, U, E)                                            \
    {                                                                 \
        const float m_ = fmaxf((A), (U));                             \
        const float d_ = (A) - (U);                                   \
        const float p_ = __builtin_amdgcn_exp2f(-fabsf(d_));          \
        const float l_ = __builtin_amdgcn_logf(1.0f + p_);            \
        (dst) = fmaf((E), L2E, m_ + l_);                              \
    }

// One block (4 waves) per batch item. Thread t owns cols [4t, 4t+3].
// Per row: coalesced 1KB vocab-row load staged through an LDS ring (the
// gather indices are row-invariant!), 4 ds_read gathers/thread, one raw
// s_barrier per row with lgkmcnt-only drain (emit loads stay in flight).
__global__ __launch_bounds__(NTH)
void align_dp4(const float* __restrict__ scores,   // [N, B, V]
               const int*   __restrict__ targets,  // [B, T]
               const int*   __restrict__ in_len,   // [B]
               const int*   __restrict__ tg_len,   // [B]
               float*       __restrict__ ws_final) // [B]
{
    constexpr float L2E = 1.44269504088896340736f;  // log2(e)
    constexpr float LN2 = 0.69314718055994530942f;

    const int b    = blockIdx.x;
    const int t    = threadIdx.x;
    const int lane = t & 63;
    const int w    = t >> 6;

    __shared__ float elds[4][VOCAB];   // emit ring: row r lives in slot r&3
    __shared__ float bnd[2][8];        // wave-boundary col values, dbuf

    const int inlen = in_len[b];
    const int tlen  = tg_len[b];

    const gcfp gsc = (gcfp)scores;
    const unsigned base = (unsigned)(b * VOCAB);
    constexpr unsigned ROWW = (unsigned)(BATCH * VOCAB);

    int tok[CPT];
#pragma unroll
    for (int c = 0; c < CPT; ++c) {
        const int col = t * CPT + c;
        tok[c] = targets[b * TARGET_LEN + (col < TARGET_LEN ? col : TARGET_LEN - 1)];
    }

    // ---- row 0 init (log2 domain): only col 0 is live ----
    float prev[CPT];
#pragma unroll
    for (int c = 0; c < CPT; ++c) prev[c] = NEGF;
    if (t == 0) prev[0] = gsc[base + (unsigned)tok[0]] * L2E;

    // ---- prologue: emit rows 1,2 direct to LDS; row-0 boundary = NEG ----
    elds[1][t] = gsc[1u * ROWW + base + (unsigned)t];
    elds[2][t] = gsc[2u * ROWW + base + (unsigned)t];
    if (lane == 63) bnd[0][w] = NEGF;

    // ---- in-flight emit loads rows 3..6; row r parked in g[r&3] ----
    float g[4];
    g[3] = gsc[3u * ROWW + base + (unsigned)t];
    g[0] = gsc[4u * ROWW + base + (unsigned)t];
    g[1] = gsc[5u * ROWW + base + (unsigned)t];
    g[2] = gsc[6u * ROWW + base + (unsigned)t];

    const int fth = (tlen - 1) >> 2;   // thread owning the final column
    const int fcc = (tlen - 1) & 3;

    // Main loop. ib ≡ 1 (mod 4), so at i = ib+K: (i+2)&3 == (K+3)&3 — the
    // register-ring index is the LITERAL (K+3)&3 (static => stays in VGPRs),
    // the LDS slot uses the runtime (i+2)&3; they agree by construction.
#define STEP(K)                                                                    \
    {                                                                              \
        const int i = ib + (K);                                                    \
        if (i < N_FRAMES) {                                                        \
            /* drain OWN lds ops only; raw barrier (no vmcnt drain!) */            \
            asm volatile("s_waitcnt lgkmcnt(0)" ::: "memory");                     \
            __builtin_amdgcn_s_barrier();                                          \
            asm volatile("" ::: "memory");                                         \
            const int sl = i & 3;                                                  \
            const float ec0 = elds[sl][tok[0]];                                    \
            const float ec1 = elds[sl][tok[1]];                                    \
            const float ec2 = elds[sl][tok[2]];                                    \
            const float ec3 = elds[sl][tok[3]];                                    \
            const float fromLds = (w > 0) ? bnd[(i - 1) & 1][w - 1] : NEGF;        \
            /* stage emit row i+2 (vmcnt-counted wait), refill with row i+6 */     \
            if (i + 2 < N_FRAMES) elds[(i + 2) & 3][t] = g[((K) + 3) & 3];         \
            if (i + 6 < N_FRAMES)                                                  \
                g[((K) + 3) & 3] = gsc[(unsigned)(i + 6) * ROWW + base + (unsigned)t]; \
            const float sh   = __shfl_up(prev[3], 1);                              \
            const float left = (lane == 0) ? fromLds : sh;                         \
            float cur0, cur1, cur2, cur3;                                          \
            CELL(cur0, left,    prev[0], ec0);                                     \
            CELL(cur1, prev[0], prev[1], ec1);                                     \
            CELL(cur2, prev[1], prev[2], ec2);                                     \
            CELL(cur3, prev[2], prev[3], ec3);                                     \
            if (lane == 63) bnd[i & 1][w] = cur3;                                  \
            if (i == inlen - 1 && t == fth) {                                      \
                const float v = (fcc == 0) ? cur0 : (fcc == 1) ? cur1              \
                              : (fcc == 2) ? cur2 : cur3;                          \
                ws_final[b] = v * LN2;                                             \
            }                                                                      \
            prev[0] = cur0; prev[1] = cur1; prev[2] = cur2; prev[3] = cur3;        \
        }                                                                          \
    }

    for (int ib = 1; ib < N_FRAMES; ib += 4) {
        STEP(0) STEP(1) STEP(2) STEP(3)
    }
#undef STEP
}

// Final scalar: out = -sum(ws_final)/BATCH. Unconditional write -> deterministic
// across graph replays regardless of buffer poisoning.
__global__ void reduce_kernel(const float* __restrict__ ws_final, float* __restrict__ out)
{
    if (threadIdx.x == 0 && blockIdx.x == 0) {
        float s = 0.0f;
        for (int b = 0; b < BATCH; ++b) s += ws_final[b];
        out[0] = -s / (float)BATCH;
    }
}

extern "C" void kernel_launch(void* const* d_in, const int* in_sizes, int n_in,
                              void* d_out, int out_size, void* d_ws, size_t ws_size,
                              hipStream_t stream)
{
    const float* scores  = (const float*)d_in[0];
    const int*   targets = (const int*)  d_in[1];
    const int*   in_len  = (const int*)  d_in[2];
    const int*   tg_len  = (const int*)  d_in[3];
    float*       out     = (float*)d_out;
    float*       ws      = (float*)d_ws;   // BATCH floats of scratch

    align_dp4<<<BATCH, NTH, 0, stream>>>(scores, targets, in_len, tg_len, ws);
    reduce_kernel<<<1, 64, 0, stream>>>(ws, out);
}